// Round 2
// baseline (769.651 us; speedup 1.0000x reference)
//
#include <hip/hip_runtime.h>
#include <hip/hip_bf16.h>
#include <stdint.h>

#define HCH 256
#define GEO 13
#define DEPTH 3
#define EPSBN 1e-5f

typedef __attribute__((ext_vector_type(8))) short short8;
typedef __attribute__((ext_vector_type(4))) float floatx4;

// fp32 -> bf16 RNE (inputs are finite; no NaN handling needed)
__device__ __forceinline__ short f2bs(float f) {
    unsigned u = __float_as_uint(f);
    unsigned r = (u + 0x7fffu + ((u >> 16) & 1u)) >> 16;
    return (short)r;
}

// ---------------- k_zero: zero output + branch counters ----------------
__global__ void k_zero(float4* out4, int n4, int* cnt) {
    int i = blockIdx.x * blockDim.x + threadIdx.x;
    if (i < n4) out4[i] = make_float4(0.f, 0.f, 0.f, 0.f);
    if (blockIdx.x == 0 && threadIdx.x < 4) cnt[threadIdx.x] = 0;
}

// ---------------- k_prep: weight transpose (LDS-coalesced) + BN fold + compaction --------
// W0t layout: [(br*25 + c)*256 + n]*32 + kk   (bf16), K padded 781->800 (25 chunks of 32)
// Wht layout: [((br*3 + l)*8 + c)*256 + n]*32 + kk (bf16)
// sc/of: (br*4 + layer)*256 + col
__global__ void k_prep(const float* __restrict__ W0, const float* __restrict__ Wh,
                       const float* __restrict__ b0, const float* __restrict__ bh,
                       const float* __restrict__ gm, const float* __restrict__ bt,
                       const float* __restrict__ mn, const float* __restrict__ vr,
                       const int* __restrict__ edx_ij, const int* __restrict__ edx_jk,
                       const int* __restrict__ nei_p,
                       short* __restrict__ W0t, short* __restrict__ Wht,
                       float* __restrict__ sc, float* __restrict__ of,
                       int* __restrict__ lists, int* __restrict__ cnt,
                       int E, int d_in_dim) {
    const int B_W0 = 100, B_WH = 96, B_SC = 16;   // W0: 4br*25chunk; Wh: 4br*3l*8chunk
    __shared__ short s[32][256];
    int b = blockIdx.x, t = threadIdx.x;
    if (b < B_W0) {
        int c = b % 25, br = b / 25;
        #pragma unroll
        for (int kk = 0; kk < 32; ++kk) {
            int kidx = c * 32 + kk;
            float v = (kidx < d_in_dim) ? W0[((size_t)br * d_in_dim + kidx) * HCH + t] : 0.f;
            s[kk][t] = f2bs(v);   // coalesced global read (n fastest)
        }
        __syncthreads();
        size_t obase = ((size_t)(br * 25 + c) * 256 + t) * 32;
        #pragma unroll
        for (int g = 0; g < 4; ++g) {
            short8 v;
            #pragma unroll
            for (int j = 0; j < 8; ++j) v[j] = s[g * 8 + j][t];
            *reinterpret_cast<short8*>(W0t + obase + g * 8) = v;   // 64B/thread, coalesced
        }
    } else if (b < B_W0 + B_WH) {
        int idx = b - B_W0;
        int c = idx & 7; idx >>= 3;
        int l = idx % 3, br = idx / 3;
        #pragma unroll
        for (int kk = 0; kk < 32; ++kk) {
            float v = Wh[((size_t)(br * DEPTH + l) * HCH + (c * 32 + kk)) * HCH + t];
            s[kk][t] = f2bs(v);
        }
        __syncthreads();
        size_t obase = ((size_t)((br * 3 + l) * 8 + c) * 256 + t) * 32;
        #pragma unroll
        for (int g = 0; g < 4; ++g) {
            short8 v;
            #pragma unroll
            for (int j = 0; j < 8; ++j) v[j] = s[g * 8 + j][t];
            *reinterpret_cast<short8*>(Wht + obase + g * 8) = v;
        }
    } else if (b < B_W0 + B_WH + B_SC) {
        int idx = (b - B_W0 - B_WH) * 256 + t; // 4096 elems
        int col = idx & 255, l = (idx >> 8) & 3, br = idx >> 10;
        int gi = (br * (DEPTH + 1) + l) * HCH + col;
        float sA = gm[gi] * rsqrtf(vr[gi] + EPSBN);
        float bias = (l == 0) ? b0[br * HCH + col] : bh[(br * DEPTH + (l - 1)) * HCH + col];
        sc[idx] = sA;
        of[idx] = (bias - mn[gi]) * sA + bt[gi];
    } else {
        // wave-aggregated branch compaction (4 atomics per wave)
        int e = (b - (B_W0 + B_WH + B_SC)) * 256 + t;
        int NEI = nei_p[0];
        int lane = t & 63;
        int br = -1;
        if (e < E)
            br = ((edx_ij[e] < NEI) ? 0 : 2) + ((edx_jk[e] < NEI) ? 0 : 1);
        unsigned long long lt = (lane == 63) ? 0x7fffffffffffffffull
                                             : ((1ull << lane) - 1ull);
        #pragma unroll
        for (int bb = 0; bb < 4; ++bb) {
            unsigned long long mk = __ballot(br == bb);
            if (mk) {
                int leader = __ffsll((long long)mk) - 1;
                int base = 0;
                if (lane == leader) base = atomicAdd(&cnt[bb], (int)__popcll(mk));
                base = __shfl(base, leader);
                if (br == bb) {
                    int pos = base + (int)__popcll(mk & lt);
                    lists[(size_t)bb * E + pos] = e;
                }
            }
        }
    }
}

// ---------------- k_main: per-branch 128-edge tile, 8 waves, 4-layer MFMA chain ----------
__global__ __launch_bounds__(512, 4)
void k_main(const float* __restrict__ node, const float* __restrict__ geo,
            const int* __restrict__ eidx, const float* __restrict__ att,
            const short* __restrict__ W0t, const short* __restrict__ Wht,
            const float* __restrict__ sc, const float* __restrict__ of,
            const int* __restrict__ lists, const int* __restrict__ cnt,
            float* __restrict__ out, int E) {
    __shared__ __align__(16) short A[128][264];   // 67.6 KB; +8 pad -> 2-way alias (free)
    __shared__ int s_i[128];
    __shared__ int s_jk[2][128];
    __shared__ int s_e[128];

    int c0 = cnt[0], c1 = cnt[1], c2 = cnt[2], c3 = cnt[3];
    int t0 = (c0 + 127) >> 7, t1 = (c1 + 127) >> 7, t2 = (c2 + 127) >> 7, t3 = (c3 + 127) >> 7;
    int b = blockIdx.x;
    int br, tile, count;
    if (b < t0)                     { br = 0; tile = b;                count = c0; }
    else if (b < t0 + t1)           { br = 1; tile = b - t0;           count = c1; }
    else if (b < t0 + t1 + t2)      { br = 2; tile = b - t0 - t1;      count = c2; }
    else if (b < t0 + t1 + t2 + t3) { br = 3; tile = b - t0 - t1 - t2; count = c3; }
    else return;
    int m = count - tile * 128; if (m > 128) m = 128;

    int t = threadIdx.x;
    if (t < 128) {
        int e = (t < m) ? lists[(size_t)br * E + (size_t)tile * 128 + t] : 0;
        s_e[t] = (t < m) ? e : -1;
        s_i[t] = eidx[e];
        s_jk[0][t] = eidx[E + e];
        s_jk[1][t] = eidx[2 * E + e];
    }
    __syncthreads();

    int wv = t >> 6, lane = t & 63, quad = lane >> 4, l16 = lane & 15;
    int rg = wv >> 2, cg = wv & 3;
    int rowbase = rg * 64;

    floatx4 acc[4][4];
    #pragma unroll
    for (int rt = 0; rt < 4; ++rt)
        #pragma unroll
        for (int ct = 0; ct < 4; ++ct)
            #pragma unroll
            for (int r = 0; r < 4; ++r) acc[rt][ct][r] = 0.f;

    int boff[4];
    #pragma unroll
    for (int ct = 0; ct < 4; ++ct)
        boff[ct] = (cg * 64 + ct * 16 + l16) * 32 + quad * 8;

    // chunk loop with B double-buffer: load c+1's fragments before MFMAs of c
    auto do_chunks = [&](const short* Wbase, int nch) {
        short8 bcur[4], bnxt[4];
        #pragma unroll
        for (int ct = 0; ct < 4; ++ct)
            bcur[ct] = *reinterpret_cast<const short8*>(Wbase + boff[ct]);
        for (int c = 0; c < nch; ++c) {
            if (c + 1 < nch) {
                const short* Bn = Wbase + (size_t)(c + 1) * 8192;
                #pragma unroll
                for (int ct = 0; ct < 4; ++ct)
                    bnxt[ct] = *reinterpret_cast<const short8*>(Bn + boff[ct]);
            }
            short8 af[4];
            #pragma unroll
            for (int rt = 0; rt < 4; ++rt)
                af[rt] = *reinterpret_cast<const short8*>(
                    &A[rowbase + rt * 16 + l16][c * 32 + quad * 8]);
            #pragma unroll
            for (int rt = 0; rt < 4; ++rt)
                #pragma unroll
                for (int ct = 0; ct < 4; ++ct)
                    acc[rt][ct] = __builtin_amdgcn_mfma_f32_16x16x32_bf16(
                        af[rt], bcur[ct], acc[rt][ct], 0, 0, 0);
            if (c + 1 < nch) {
                #pragma unroll
                for (int ct = 0; ct < 4; ++ct) bcur[ct] = bnxt[ct];
            }
        }
    };

    // ---------------- layer 0: x = [nf[i] | nf[j] | nf[k] | geo_pad] @ W0 ----------------
    for (int p = 0; p < 4; ++p) {
        __syncthreads();  // previous part's A reads done
        if (p < 3) {
            const int* idxs = (p == 0) ? s_i : s_jk[p - 1];
            #pragma unroll
            for (int it = 0; it < 8; ++it) {
                int job = it * 512 + t;          // 128 rows x 32 chunks of 8 floats
                int row = job >> 5, cc = job & 31;
                const float4* src = reinterpret_cast<const float4*>(
                    node + (size_t)idxs[row] * HCH + cc * 8);
                float4 v0 = src[0], v1 = src[1];
                short8 pk;
                pk[0] = f2bs(v0.x); pk[1] = f2bs(v0.y); pk[2] = f2bs(v0.z); pk[3] = f2bs(v0.w);
                pk[4] = f2bs(v1.x); pk[5] = f2bs(v1.y); pk[6] = f2bs(v1.z); pk[7] = f2bs(v1.w);
                *reinterpret_cast<short8*>(&A[row][cc * 8]) = pk;
            }
        } else {
            if (t < 128) {
                int e = s_e[t];
                #pragma unroll
                for (int kk = 0; kk < 32; ++kk) {
                    float v = (kk < GEO && e >= 0) ? geo[(size_t)e * GEO + kk] : 0.f;
                    A[t][kk] = f2bs(v);
                }
            }
        }
        __syncthreads();
        do_chunks(W0t + (size_t)(br * 25 + ((p < 3) ? p * 8 : 24)) * 8192, (p < 3) ? 8 : 1);
    }

    // ---------------- BN+relu epilogues, hidden layers, final scatter ----------------
    for (int l = 0; l < 4; ++l) {
        float sv[4], ov[4];
        #pragma unroll
        for (int ct = 0; ct < 4; ++ct) {
            int col = cg * 64 + ct * 16 + l16;
            sv[ct] = sc[(br * 4 + l) * HCH + col];
            ov[ct] = of[(br * 4 + l) * HCH + col];
        }
        if (l < 3) {
            __syncthreads();  // matmul's A reads done before overwrite
            #pragma unroll
            for (int rt = 0; rt < 4; ++rt)
                #pragma unroll
                for (int ct = 0; ct < 4; ++ct) {
                    int col = cg * 64 + ct * 16 + l16;
                    #pragma unroll
                    for (int r = 0; r < 4; ++r) {
                        float h = fmaxf(acc[rt][ct][r] * sv[ct] + ov[ct], 0.f);
                        A[rowbase + rt * 16 + quad * 4 + r][col] = f2bs(h);
                        acc[rt][ct][r] = 0.f;
                    }
                }
            __syncthreads();
            do_chunks(Wht + (size_t)((br * 3 + l) * 8) * 8192, 8);
        } else {
            // final: relu -> leaky_relu (identity on >=0) -> *att -> scatter-add on node i
            float av = att[br];
            #pragma unroll
            for (int rt = 0; rt < 4; ++rt)
                #pragma unroll
                for (int r = 0; r < 4; ++r) {
                    int row = rowbase + rt * 16 + quad * 4 + r;
                    if (row < m) {
                        float* orow = out + (size_t)s_i[row] * HCH + cg * 64 + l16;
                        #pragma unroll
                        for (int ct = 0; ct < 4; ++ct) {
                            float h = fmaxf(acc[rt][ct][r] * sv[ct] + ov[ct], 0.f);
                            atomicAdd(orow + ct * 16, h * av);
                        }
                    }
                }
        }
    }
}

// ---------------- host launcher ----------------
extern "C" void kernel_launch(void* const* d_in, const int* in_sizes, int n_in,
                              void* d_out, int out_size, void* d_ws, size_t ws_size,
                              hipStream_t stream) {
    const float* node  = (const float*)d_in[0];
    const float* geo   = (const float*)d_in[1];
    const int*   eidx  = (const int*)d_in[2];
    const int*   edxij = (const int*)d_in[3];
    const int*   edxjk = (const int*)d_in[4];
    const float* att   = (const float*)d_in[5];
    const float* W0    = (const float*)d_in[6];
    const float* b0    = (const float*)d_in[7];
    const float* Wh    = (const float*)d_in[8];
    const float* bh    = (const float*)d_in[9];
    const float* gm    = (const float*)d_in[10];
    const float* bt    = (const float*)d_in[11];
    const float* mn    = (const float*)d_in[12];
    const float* vr    = (const float*)d_in[13];
    const int*   neip  = (const int*)d_in[14];

    int E = in_sizes[3];
    int d_in_dim = in_sizes[6] / (4 * HCH);   // 781

    uint8_t* w = (uint8_t*)d_ws;
    size_t sz0 = (size_t)4 * 25 * 256 * 32 * 2;     // W0t bf16
    size_t sz1 = (size_t)4 * 3 * 8 * 256 * 32 * 2;  // Wht bf16
    size_t sz2 = (size_t)4096 * 4;                  // sc
    size_t sz3 = (size_t)4096 * 4;                  // of
    size_t sz4 = (size_t)4 * E * 4;                 // lists
    short* W0t  = (short*)w;
    short* Wht  = (short*)(w + sz0);
    float* sc   = (float*)(w + sz0 + sz1);
    float* of   = (float*)(w + sz0 + sz1 + sz2);
    int*   lists= (int*)(w + sz0 + sz1 + sz2 + sz3);
    int*   cnt  = (int*)(w + sz0 + sz1 + sz2 + sz3 + sz4);

    float* out = (float*)d_out;
    int n4 = out_size / 4;
    k_zero<<<(n4 + 255) / 256, 256, 0, stream>>>((float4*)out, n4, cnt);

    int BCM = (E + 255) / 256;
    k_prep<<<100 + 96 + 16 + BCM, 256, 0, stream>>>(
        W0, Wh, b0, bh, gm, bt, mn, vr, edxij, edxjk, neip,
        W0t, Wht, sc, of, lists, cnt, E, d_in_dim);

    int T = (E >> 7) + 8;
    k_main<<<T, 512, 0, stream>>>(node, geo, eidx, att, W0t, Wht,
                                  sc, of, lists, cnt, out, E);
}

// Round 3
// 384.763 us; speedup vs baseline: 2.0003x; 2.0003x over previous
//
#include <hip/hip_runtime.h>
#include <hip/hip_bf16.h>
#include <stdint.h>

#define HCH 256
#define GEO 13
#define DEPTH 3
#define EPSBN 1e-5f

typedef __attribute__((ext_vector_type(8))) short short8;
typedef __attribute__((ext_vector_type(4))) float floatx4;

// fp32 -> bf16 RNE
__device__ __forceinline__ short f2bs(float f) {
    unsigned u = __float_as_uint(f);
    unsigned r = (u + 0x7fffu + ((u >> 16) & 1u)) >> 16;
    return (short)r;
}

// ---------------- k_zero: zero output + branch counters ----------------
__global__ void k_zero(float4* out4, int n4, int* cnt) {
    int i = blockIdx.x * blockDim.x + threadIdx.x;
    if (i < n4) out4[i] = make_float4(0.f, 0.f, 0.f, 0.f);
    if (blockIdx.x == 0 && threadIdx.x < 4) cnt[threadIdx.x] = 0;
}

// ---------------- k_prep: weights->bf16 (transposed), node/geo->bf16, BN fold, compaction
// W0t: [(br*25 + c)*256 + n]*32 + kk  (bf16), K padded 781->800
// Wht: [((br*3 + l)*8 + c)*256 + n]*32 + kk
// sc/of: (br*4 + layer)*256 + col   (layer 3 pre-multiplied by att[br])
// node_bf: [N][256] bf16 ; geo_bf: [E][32] bf16 zero-padded
__global__ void k_prep(const float* __restrict__ W0, const float* __restrict__ Wh,
                       const float* __restrict__ b0, const float* __restrict__ bh,
                       const float* __restrict__ gm, const float* __restrict__ bt,
                       const float* __restrict__ mn, const float* __restrict__ vr,
                       const float* __restrict__ att,
                       const float* __restrict__ node, const float* __restrict__ geo,
                       const int* __restrict__ edx_ij, const int* __restrict__ edx_jk,
                       const int* __restrict__ nei_p,
                       short* __restrict__ W0t, short* __restrict__ Wht,
                       float* __restrict__ sc, float* __restrict__ of,
                       short* __restrict__ node_bf, short* __restrict__ geo_bf,
                       int* __restrict__ lists, int* __restrict__ cnt,
                       int E, int d_in_dim, int nb_node, int nb_geo) {
    const int B_W0 = 100, B_WH = 96, B_SC = 16;
    __shared__ short s[32][256];
    int b = blockIdx.x, t = threadIdx.x;
    if (b < B_W0) {
        int c = b % 25, br = b / 25;
        #pragma unroll
        for (int kk = 0; kk < 32; ++kk) {
            int kidx = c * 32 + kk;
            float v = (kidx < d_in_dim) ? W0[((size_t)br * d_in_dim + kidx) * HCH + t] : 0.f;
            s[kk][t] = f2bs(v);   // coalesced global read (n fastest)
        }
        __syncthreads();
        size_t obase = ((size_t)(b) * 256 + t) * 32;
        #pragma unroll
        for (int g = 0; g < 4; ++g) {
            short8 v;
            #pragma unroll
            for (int j = 0; j < 8; ++j) v[j] = s[g * 8 + j][t];
            *reinterpret_cast<short8*>(W0t + obase + g * 8) = v;
        }
    } else if (b < B_W0 + B_WH) {
        int idx = b - B_W0;
        int c = idx & 7; idx >>= 3;
        int l = idx % 3, br = idx / 3;
        #pragma unroll
        for (int kk = 0; kk < 32; ++kk) {
            float v = Wh[((size_t)(br * DEPTH + l) * HCH + (c * 32 + kk)) * HCH + t];
            s[kk][t] = f2bs(v);
        }
        __syncthreads();
        size_t obase = ((size_t)(b - B_W0) * 256 + t) * 32;
        #pragma unroll
        for (int g = 0; g < 4; ++g) {
            short8 v;
            #pragma unroll
            for (int j = 0; j < 8; ++j) v[j] = s[g * 8 + j][t];
            *reinterpret_cast<short8*>(Wht + obase + g * 8) = v;
        }
    } else if (b < B_W0 + B_WH + B_SC) {
        int idx = (b - B_W0 - B_WH) * 256 + t; // 4096 elems
        int col = idx & 255, l = (idx >> 8) & 3, br = idx >> 10;
        int gi = (br * (DEPTH + 1) + l) * HCH + col;
        float sA = gm[gi] * rsqrtf(vr[gi] + EPSBN);
        float bias = (l == 0) ? b0[br * HCH + col] : bh[(br * DEPTH + (l - 1)) * HCH + col];
        float ofv = (bias - mn[gi]) * sA + bt[gi];
        if (l == 3) { float av = att[br]; sA *= av; ofv *= av; }  // fold att (relu out >=0)
        sc[idx] = sA;
        of[idx] = ofv;
    } else if (b < B_W0 + B_WH + B_SC + nb_node) {
        // node fp32 -> bf16, 8 elems/thread, coalesced
        size_t i = ((size_t)(b - B_W0 - B_WH - B_SC) * 256 + t) * 8;
        const float4* src = reinterpret_cast<const float4*>(node + i);
        float4 v0 = src[0], v1 = src[1];
        short8 pk;
        pk[0] = f2bs(v0.x); pk[1] = f2bs(v0.y); pk[2] = f2bs(v0.z); pk[3] = f2bs(v0.w);
        pk[4] = f2bs(v1.x); pk[5] = f2bs(v1.y); pk[6] = f2bs(v1.z); pk[7] = f2bs(v1.w);
        *reinterpret_cast<short8*>(node_bf + i) = pk;
    } else if (b < B_W0 + B_WH + B_SC + nb_node + nb_geo) {
        // geo [E][13] fp32 -> [E][32] bf16 zero-padded
        int i = (b - B_W0 - B_WH - B_SC - nb_node) * 256 + t;
        int e = i >> 2, cc = i & 3;
        if (e < E) {
            short8 pk;
            #pragma unroll
            for (int j = 0; j < 8; ++j) {
                int col = cc * 8 + j;
                pk[j] = (col < GEO) ? f2bs(geo[(size_t)e * GEO + col]) : (short)0;
            }
            *reinterpret_cast<short8*>(geo_bf + (size_t)e * 32 + cc * 8) = pk;
        }
    } else {
        // wave-aggregated branch compaction (4 atomics per wave)
        int e = (b - (B_W0 + B_WH + B_SC + nb_node + nb_geo)) * 256 + t;
        int NEI = nei_p[0];
        int lane = t & 63;
        int br = -1;
        if (e < E)
            br = ((edx_ij[e] < NEI) ? 0 : 2) + ((edx_jk[e] < NEI) ? 0 : 1);
        unsigned long long lt = (lane == 63) ? 0x7fffffffffffffffull
                                             : ((1ull << lane) - 1ull);
        #pragma unroll
        for (int bb = 0; bb < 4; ++bb) {
            unsigned long long mk = __ballot(br == bb);
            if (mk) {
                int leader = __ffsll((long long)mk) - 1;
                int base = 0;
                if (lane == leader) base = atomicAdd(&cnt[bb], (int)__popcll(mk));
                base = __shfl(base, leader);
                if (br == bb) {
                    int pos = base + (int)__popcll(mk & lt);
                    lists[(size_t)bb * E + pos] = e;
                }
            }
        }
    }
}

// ---------------- k_main: 64-edge tile, 8 waves (64x32 each), 4-layer MFMA chain ----------
__global__ __launch_bounds__(512)
void k_main(const short* __restrict__ node_bf, const short* __restrict__ geo_bf,
            const int* __restrict__ eidx,
            const short* __restrict__ W0t, const short* __restrict__ Wht,
            const float* __restrict__ sc, const float* __restrict__ of,
            const int* __restrict__ lists, const int* __restrict__ cnt,
            float* __restrict__ out, int E) {
    __shared__ __align__(16) short A[64][264];   // 33.8 KB
    __shared__ int s_i[64];
    __shared__ int s_jk[2][64];
    __shared__ int s_e[64];

    int c0 = cnt[0], c1 = cnt[1], c2 = cnt[2], c3 = cnt[3];
    int t0 = (c0 + 63) >> 6, t1 = (c1 + 63) >> 6, t2 = (c2 + 63) >> 6, t3 = (c3 + 63) >> 6;
    int b = blockIdx.x;
    int br, tile, count;
    if (b < t0)                     { br = 0; tile = b;                count = c0; }
    else if (b < t0 + t1)           { br = 1; tile = b - t0;           count = c1; }
    else if (b < t0 + t1 + t2)      { br = 2; tile = b - t0 - t1;      count = c2; }
    else if (b < t0 + t1 + t2 + t3) { br = 3; tile = b - t0 - t1 - t2; count = c3; }
    else return;
    int m = count - tile * 64; if (m > 64) m = 64;

    int t = threadIdx.x;
    if (t < 64) {
        int e = (t < m) ? lists[(size_t)br * E + (size_t)tile * 64 + t] : 0;
        s_e[t] = (t < m) ? e : -1;
        s_i[t] = eidx[e];
        s_jk[0][t] = eidx[E + e];
        s_jk[1][t] = eidx[2 * E + e];
    }
    __syncthreads();

    int wv = t >> 6, lane = t & 63, quad = lane >> 4, l16 = lane & 15;

    floatx4 acc[4][2];
    #pragma unroll
    for (int rt = 0; rt < 4; ++rt)
        #pragma unroll
        for (int ct = 0; ct < 2; ++ct)
            #pragma unroll
            for (int r = 0; r < 4; ++r) acc[rt][ct][r] = 0.f;

    int boff[2];
    #pragma unroll
    for (int ct = 0; ct < 2; ++ct)
        boff[ct] = (wv * 32 + ct * 16 + l16) * 32 + quad * 8;

    // chunk loop with 1-deep B prefetch
    auto do_chunks = [&](const short* Wbase, int nch) {
        short8 bcur[2], bnxt[2];
        #pragma unroll
        for (int ct = 0; ct < 2; ++ct)
            bcur[ct] = *reinterpret_cast<const short8*>(Wbase + boff[ct]);
        for (int c = 0; c < nch; ++c) {
            if (c + 1 < nch) {
                const short* Bn = Wbase + (size_t)(c + 1) * 8192;
                #pragma unroll
                for (int ct = 0; ct < 2; ++ct)
                    bnxt[ct] = *reinterpret_cast<const short8*>(Bn + boff[ct]);
            }
            short8 af[4];
            #pragma unroll
            for (int rt = 0; rt < 4; ++rt)
                af[rt] = *reinterpret_cast<const short8*>(&A[rt * 16 + l16][c * 32 + quad * 8]);
            #pragma unroll
            for (int rt = 0; rt < 4; ++rt)
                #pragma unroll
                for (int ct = 0; ct < 2; ++ct)
                    acc[rt][ct] = __builtin_amdgcn_mfma_f32_16x16x32_bf16(
                        af[rt], bcur[ct], acc[rt][ct], 0, 0, 0);
            if (c + 1 < nch) {
                #pragma unroll
                for (int ct = 0; ct < 2; ++ct) bcur[ct] = bnxt[ct];
            }
        }
    };

    // ---------------- layer 0: x = [nf[i] | nf[j] | nf[k] | geo_pad] @ W0 ----------------
    for (int p = 0; p < 4; ++p) {
        __syncthreads();  // previous part's A reads done
        if (p < 3) {
            const int* idxs = (p == 0) ? s_i : s_jk[p - 1];
            #pragma unroll
            for (int it = 0; it < 4; ++it) {
                int job = it * 512 + t;          // 64 rows x 32 chunks of 8 bf16
                int row = job >> 5, cc = job & 31;
                short8 v = *reinterpret_cast<const short8*>(
                    node_bf + (size_t)idxs[row] * HCH + cc * 8);
                *reinterpret_cast<short8*>(&A[row][cc * 8]) = v;
            }
        } else {
            if (t < 256) {
                int row = t >> 2, cc = t & 3;
                int e = s_e[row];
                short8 v;
                if (e >= 0)
                    v = *reinterpret_cast<const short8*>(geo_bf + (size_t)e * 32 + cc * 8);
                else
                    #pragma unroll
                    for (int j = 0; j < 8; ++j) v[j] = 0;
                *reinterpret_cast<short8*>(&A[row][cc * 8]) = v;
            }
        }
        __syncthreads();
        do_chunks(W0t + (size_t)(br * 25 + ((p < 3) ? p * 8 : 24)) * 8192, (p < 3) ? 8 : 1);
    }

    // ---------------- BN+relu epilogues, hidden layers, final scatter ----------------
    for (int l = 0; l < 4; ++l) {
        float sv[2], ov[2];
        #pragma unroll
        for (int ct = 0; ct < 2; ++ct) {
            int col = wv * 32 + ct * 16 + l16;
            sv[ct] = sc[(br * 4 + l) * HCH + col];
            ov[ct] = of[(br * 4 + l) * HCH + col];
        }
        if (l < 3) {
            __syncthreads();  // matmul's A reads done before overwrite
            #pragma unroll
            for (int rt = 0; rt < 4; ++rt)
                #pragma unroll
                for (int ct = 0; ct < 2; ++ct) {
                    int col = wv * 32 + ct * 16 + l16;
                    #pragma unroll
                    for (int r = 0; r < 4; ++r) {
                        float h = fmaxf(acc[rt][ct][r] * sv[ct] + ov[ct], 0.f);
                        A[rt * 16 + quad * 4 + r][col] = f2bs(h);
                        acc[rt][ct][r] = 0.f;
                    }
                }
            __syncthreads();
            do_chunks(Wht + (size_t)((br * 3 + l) * 8) * 8192, 8);
        } else {
            // final: relu (leaky+att folded into sc/of) -> scatter-add on node i
            #pragma unroll
            for (int rt = 0; rt < 4; ++rt)
                #pragma unroll
                for (int r = 0; r < 4; ++r) {
                    int row = rt * 16 + quad * 4 + r;
                    if (row < m) {
                        float* orow = out + (size_t)s_i[row] * HCH + wv * 32 + l16;
                        #pragma unroll
                        for (int ct = 0; ct < 2; ++ct) {
                            float h = fmaxf(acc[rt][ct][r] * sv[ct] + ov[ct], 0.f);
                            atomicAdd(orow + ct * 16, h);
                        }
                    }
                }
        }
    }
}

// ---------------- host launcher ----------------
extern "C" void kernel_launch(void* const* d_in, const int* in_sizes, int n_in,
                              void* d_out, int out_size, void* d_ws, size_t ws_size,
                              hipStream_t stream) {
    const float* node  = (const float*)d_in[0];
    const float* geo   = (const float*)d_in[1];
    const int*   eidx  = (const int*)d_in[2];
    const int*   edxij = (const int*)d_in[3];
    const int*   edxjk = (const int*)d_in[4];
    const float* att   = (const float*)d_in[5];
    const float* W0    = (const float*)d_in[6];
    const float* b0    = (const float*)d_in[7];
    const float* Wh    = (const float*)d_in[8];
    const float* bh    = (const float*)d_in[9];
    const float* gm    = (const float*)d_in[10];
    const float* bt    = (const float*)d_in[11];
    const float* mn    = (const float*)d_in[12];
    const float* vr    = (const float*)d_in[13];
    const int*   neip  = (const int*)d_in[14];

    int E = in_sizes[3];
    int N = in_sizes[0] / HCH;
    int d_in_dim = in_sizes[6] / (4 * HCH);   // 781

    uint8_t* w = (uint8_t*)d_ws;
    size_t off = 0;
    short* W0t  = (short*)(w + off); off += (size_t)4 * 25 * 256 * 32 * 2;
    short* Wht  = (short*)(w + off); off += (size_t)4 * 3 * 8 * 256 * 32 * 2;
    float* sc   = (float*)(w + off); off += 4096 * 4;
    float* of   = (float*)(w + off); off += 4096 * 4;
    int*   lists= (int*)(w + off);   off += (size_t)4 * E * 4;
    int*   cnt  = (int*)(w + off);   off += 16;
    short* node_bf = (short*)(w + off); off += (size_t)N * HCH * 2;
    short* geo_bf  = (short*)(w + off); off += (size_t)E * 32 * 2;

    float* out = (float*)d_out;
    int n4 = out_size / 4;
    k_zero<<<(n4 + 255) / 256, 256, 0, stream>>>((float4*)out, n4, cnt);

    int nb_node = N / 8;                 // N*256 elems / (256 thr * 8)
    int nb_geo  = (4 * E + 255) / 256;
    int nb_cmp  = (E + 255) / 256;
    k_prep<<<100 + 96 + 16 + nb_node + nb_geo + nb_cmp, 256, 0, stream>>>(
        W0, Wh, b0, bh, gm, bt, mn, vr, att, node, geo, edxij, edxjk, neip,
        W0t, Wht, sc, of, node_bf, geo_bf, lists, cnt, E, d_in_dim, nb_node, nb_geo);

    int T = (E >> 6) + 8;
    k_main<<<T, 512, 0, stream>>>(node_bf, geo_bf, eidx, W0t, Wht,
                                  sc, of, lists, cnt, out, E);
}